// Round 9
// baseline (1185.469 us; speedup 1.0000x reference)
//
#include <hip/hip_runtime.h>

#define N_NODES 50000
#define N_EDGES 800000
#define DIM 256
#define NG 64
#define EPS_BN 1e-5f
#define NB_AGG 3125
#define NB_COL 512
#define NRG 391          // row-groups for sliced gcn_agg; grid = NRG*8

typedef _Float16 f16;
typedef _Float16 half8 __attribute__((ext_vector_type(8)));
typedef _Float16 half4 __attribute__((ext_vector_type(4)));
typedef _Float16 half2 __attribute__((ext_vector_type(2)));
typedef float floatx4 __attribute__((ext_vector_type(4)));

__device__ __forceinline__ int fkey(float f) { int i = __float_as_int(f); return (i >= 0) ? i : (i ^ 0x7fffffff); }
__device__ __forceinline__ float keyf(int k) { return __int_as_float((k >= 0) ? k : (k ^ 0x7fffffff)); }

// ============================ input BN statistics -> coalesced per-block partials ============================
__global__ __launch_bounds__(256) void col_stats_kernel(const float* __restrict__ X, int n,
                                                        float* __restrict__ part) {
    int c = threadIdx.x;
    float s = 0.f, q = 0.f;
    for (int i = blockIdx.x; i < n; i += gridDim.x) {
        float v = X[(size_t)i * DIM + c];
        s += v; q += v * v;
    }
    part[(size_t)blockIdx.x * 512 + c] = s;
    part[(size_t)blockIdx.x * 512 + DIM + c] = q;
}

// single-block reduce+finalize for input BN: affine A[c]=rstd*g, B[c]=b-mean*A
__global__ __launch_bounds__(256) void reduce_in_finalize_kernel(const float* __restrict__ part,
                                                                 const float* __restrict__ g, const float* __restrict__ b,
                                                                 float* __restrict__ affine, float inv_n) {
    int c = threadIdx.x;
    float s = 0.f, q = 0.f;
    for (int r = 0; r < NB_COL; r++) {
        s += part[(size_t)r * 512 + c];
        q += part[(size_t)r * 512 + DIM + c];
    }
    float m = s * inv_n;
    float v = q * inv_n - m * m;
    float rstd = rsqrtf(v + EPS_BN);
    float A = rstd * g[c];
    affine[c] = A;
    affine[DIM + c] = b[c] - m * A;
}

// single-block reduce+finalize for layer stats (sliced layout: part[blk*64 + {i32, 32+i32}], blk = rg*8+slice)
__global__ __launch_bounds__(256) void reduce_agg_finalize_kernel(const float* __restrict__ part,
                                                                  const float* __restrict__ g, const float* __restrict__ b,
                                                                  float* __restrict__ affine, float inv_n) {
    int c = threadIdx.x;          // 0..255
    int s_ = c >> 5, i32 = c & 31;
    float s = 0.f, q = 0.f;
    for (int rg = 0; rg < NRG; rg++) {
        size_t base = (size_t)(rg * 8 + s_) * 64;
        s += part[base + i32];
        q += part[base + 32 + i32];
    }
    float m = s * inv_n;
    float v = q * inv_n - m * m;
    float rstd = rsqrtf(v + EPS_BN);
    float A = rstd * g[c];
    affine[c] = A;
    affine[DIM + c] = b[c] - m * A;
}

// ============================ weight conversion, all 4 in one ============================
__global__ void convert_all_kernel(const float* __restrict__ W0, const float* __restrict__ W1,
                                   const float* __restrict__ W2, const float* __restrict__ Wa1,
                                   f16* __restrict__ T0, f16* __restrict__ T1,
                                   f16* __restrict__ T2, f16* __restrict__ T3) {
    int idx = blockIdx.x * 256 + threadIdx.x;
    if (idx < 196608) {
        int w = idx >> 16, r = idx & 65535;
        const float* W = (w == 0) ? W0 : (w == 1) ? W1 : W2;
        f16* T = (w == 0) ? T0 : (w == 1) ? T1 : T2;
        int m = r >> 8, k = r & 255;
        T[r] = (f16)W[(size_t)k * 256 + m];
    } else {
        int r = idx - 196608;
        int m = r >> 8, k = r & 255;
        T3[r] = (f16)Wa1[(size_t)k * 128 + m];
    }
}

// ============== degree histogram (saving local positions) + graph bounds (merged) ==============
__global__ void count_bounds_kernel(const int* __restrict__ dst, int ne, int* __restrict__ cnt,
                                    int* __restrict__ lpos,
                                    const int* __restrict__ batch, int n, int* __restrict__ start) {
    int gb = blockIdx.x;
    if (gb < NB_AGG) {
        for (int i = gb * 256 + threadIdx.x; i < ne; i += NB_AGG * 256)
            lpos[i] = atomicAdd(&cnt[dst[i]], 1);
    } else {
        int i = (gb - NB_AGG) * 256 + threadIdx.x;
        if (i < n) {
            int b = batch[i];
            if (i == 0 || batch[i - 1] != b) start[b] = i;
        }
    }
}

#define SCHUNK 2048
__global__ __launch_bounds__(256) void scan1_kernel(const int* __restrict__ cnt, int n,
                                                    int* __restrict__ outp, int* __restrict__ bsums,
                                                    float* __restrict__ dinv) {
    __shared__ int lds[256];
    int t = threadIdx.x;
    int base = blockIdx.x * SCHUNK + t * 8;
    int v[8]; int s = 0;
#pragma unroll
    for (int j = 0; j < 8; j++) {
        int id = base + j;
        int x = 0;
        if (id < n) { x = cnt[id]; dinv[id] = rsqrtf((float)x + 1.0f); }
        v[j] = s; s += x;
    }
    lds[t] = s; __syncthreads();
    for (int o = 1; o < 256; o <<= 1) {
        int add = (t >= o) ? lds[t - o] : 0;
        __syncthreads();
        lds[t] += add;
        __syncthreads();
    }
    int excl = lds[t] - s;
#pragma unroll
    for (int j = 0; j < 8; j++) { int id = base + j; if (id < n) outp[id] = excl + v[j]; }
    if (t == 255) bsums[blockIdx.x] = lds[255];
}

__global__ void scan3_kernel(int* __restrict__ outp, const int* __restrict__ bsums, int n, int total) {
    int i = blockIdx.x * blockDim.x + threadIdx.x;
    if (i < n) {
        int k = i / SCHUNK;
        int pref = 0;
        for (int j = 0; j < k; j++) pref += bsums[j];
        outp[i] += pref;
    }
    if (i == 0) outp[n] = total;
}

// atomic-free scatter using saved local positions
__global__ void scatter_kernel(const int* __restrict__ src, const int* __restrict__ dst,
                               const int* __restrict__ lpos, int ne,
                               const int* __restrict__ rowp, int* __restrict__ ss) {
    for (int e = blockIdx.x * blockDim.x + threadIdx.x; e < ne; e += gridDim.x * blockDim.x)
        ss[rowp[dst[e]] + lpos[e]] = src[e];
}

__global__ void graph_offsets2_kernel(const int* __restrict__ start, int* __restrict__ off, int* __restrict__ cnt,
                                      int* __restrict__ maxkey) {
    if (threadIdx.x == 0 && blockIdx.x == 0) {
        int nxt = N_NODES;
        for (int g = NG - 1; g >= 0; --g) {
            int s = start[g];
            int o = (s < 0) ? nxt : s;
            off[g] = o;
            cnt[g] = nxt - o;
            nxt = o;
        }
        maxkey[0] = 0x80000000;
    }
}

// ============================ GCN edge aggregation — XCD column-sliced ============================
// Block slice = blockIdx&7 (XCD heuristic) handles 32 columns of all rows in its row-groups.
// Per-XCD h working set = 3.2 MB -> fits 4 MB L2. Lane groups of 16 process 4 edges/instruction.
// h is pre-scaled by dinv. out = dinv[row]*(sum + h[row]) + bias. Stats partials: part[blk*64+..]
__global__ __launch_bounds__(256) void gcn_agg_kernel(const f16* __restrict__ h, const int* __restrict__ rowp,
                                                      const int* __restrict__ ss, const float* __restrict__ dinv,
                                                      const float* __restrict__ bias, f16* __restrict__ out,
                                                      float* __restrict__ part, int n) {
    int blk = blockIdx.x;
    int slice = blk & 7;
    int rowgrp = blk >> 3;
    int tid = threadIdx.x;
    int wave = tid >> 6, lane = tid & 63;
    int g = lane >> 4, t = lane & 15;
    int colbase = slice * 32 + t * 2;    // halfs
    float b0 = bias[colbase], b1 = bias[colbase + 1];
    float s0 = 0.f, s1 = 0.f, q0 = 0.f, q1 = 0.f;
    for (int row = rowgrp * 4 + wave; row < n; row += NRG * 4) {
        int e0 = rowp[row], e1 = rowp[row + 1];
        float a0 = 0.f, a1 = 0.f;
        int e = e0 + g;
        for (; e + 4 < e1; e += 8) {
            int sA = __builtin_nontemporal_load(&ss[e]);
            int sB = __builtin_nontemporal_load(&ss[e + 4]);
            half2 vA = *(const half2*)&h[((size_t)sA << 8) + colbase];
            half2 vB = *(const half2*)&h[((size_t)sB << 8) + colbase];
            a0 += (float)vA[0] + (float)vB[0];
            a1 += (float)vA[1] + (float)vB[1];
        }
        if (e < e1) {
            int sA = __builtin_nontemporal_load(&ss[e]);
            half2 vA = *(const half2*)&h[((size_t)sA << 8) + colbase];
            a0 += (float)vA[0];
            a1 += (float)vA[1];
        }
        // combine the 4 lane-groups (lanes t, t+16, t+32, t+48)
        a0 += __shfl_xor(a0, 16); a0 += __shfl_xor(a0, 32);
        a1 += __shfl_xor(a1, 16); a1 += __shfl_xor(a1, 32);
        if (g == 0) {
            float di = dinv[row];
            half2 hs = *(const half2*)&h[((size_t)row << 8) + colbase];
            float r0 = di * (a0 + (float)hs[0]) + b0;
            float r1 = di * (a1 + (float)hs[1]) + b1;
            half2 o; o[0] = (f16)r0; o[1] = (f16)r1;
            *(half2*)&out[((size_t)row << 8) + colbase] = o;
            float u;
            u = fmaxf(r0, 0.f); s0 += u; q0 += u * u;
            u = fmaxf(r1, 0.f); s1 += u; q1 += u * u;
        }
    }
    __shared__ float sred[4][16][4];
    if (g == 0) { sred[wave][t][0] = s0; sred[wave][t][1] = s1; sred[wave][t][2] = q0; sred[wave][t][3] = q1; }
    __syncthreads();
    if (tid < 16) {
        float S0 = 0.f, S1 = 0.f, Q0 = 0.f, Q1 = 0.f;
#pragma unroll
        for (int w2 = 0; w2 < 4; w2++) {
            S0 += sred[w2][tid][0]; S1 += sred[w2][tid][1];
            Q0 += sred[w2][tid][2]; Q1 += sred[w2][tid][3];
        }
        size_t base = (size_t)blk * 64;
        part[base + tid * 2] = S0;
        part[base + tid * 2 + 1] = S1;
        part[base + 32 + tid * 2] = Q0;
        part[base + 32 + tid * 2 + 1] = Q1;
    }
}

// ============================ fused BN + MFMA GEMM ============================
#define BM 128
#define BN 128
#define BK 32
#define LDP 40
__global__ __launch_bounds__(256) void gemm_fused_kernel(const float* __restrict__ Xf32, const f16* __restrict__ Ch,
                                                         const f16* __restrict__ Aold, f16* __restrict__ Afout,
                                                         const float* __restrict__ affine,
                                                         const f16* __restrict__ Wt, f16* __restrict__ Cout,
                                                         const float* __restrict__ scale, int n, int K, int M) {
    __shared__ __align__(16) f16 As[BM * LDP];
    __shared__ __align__(16) f16 Bs[BN * LDP];
    __shared__ float sA[256], sB[256];
    int tid = threadIdx.x;
    if (tid < 256) { sA[tid] = affine[tid]; sB[tid] = affine[256 + tid]; }
    int wave = tid >> 6, lane = tid & 63;
    int wm = wave >> 1, wn = wave & 1;
    int q = lane >> 4, l16 = lane & 15;
    int bm = blockIdx.x * BM, bn = blockIdx.y * BN;
    int kc = (tid & 3) * 8;
    int writer = (Afout != nullptr) && (blockIdx.y == 0);
    floatx4 acc[4][4] = {};
    __syncthreads();
    for (int k0 = 0; k0 < K; k0 += BK) {
        float a8[8], b8[8];
#pragma unroll
        for (int j = 0; j < 8; j++) { a8[j] = sA[k0 + kc + j]; b8[j] = sB[k0 + kc + j]; }
#pragma unroll
        for (int rr = 0; rr < 2; rr++) {
            int cidx = tid + rr * 256;
            int row = cidx >> 2;
            int arow = bm + row; if (arow >= n) arow = n - 1;
            float v[8];
            if (Xf32) {
                float4 x0 = *(const float4*)&Xf32[(size_t)arow * K + k0 + kc];
                float4 x1 = *(const float4*)&Xf32[(size_t)arow * K + k0 + kc + 4];
                v[0] = x0.x; v[1] = x0.y; v[2] = x0.z; v[3] = x0.w;
                v[4] = x1.x; v[5] = x1.y; v[6] = x1.z; v[7] = x1.w;
            } else {
                half8 ch = *(const half8*)&Ch[(size_t)arow * K + k0 + kc];
#pragma unroll
                for (int j = 0; j < 8; j++) v[j] = fmaxf((float)ch[j], 0.f);
            }
            half8 af;
            if (Aold) {
                half8 ao = *(const half8*)&Aold[(size_t)arow * K + k0 + kc];
#pragma unroll
                for (int j = 0; j < 8; j++) af[j] = (f16)(v[j] * a8[j] + b8[j] + (float)ao[j]);
            } else {
#pragma unroll
                for (int j = 0; j < 8; j++) af[j] = (f16)(v[j] * a8[j] + b8[j]);
            }
            *(float4*)&As[row * LDP + kc] = *(float4*)&af;
            if (writer && bm + row < n) *(half8*)&Afout[(size_t)arow * K + k0 + kc] = af;
            int brow = bn + row;
            *(float4*)&Bs[row * LDP + kc] = *(const float4*)&Wt[(size_t)brow * K + k0 + kc];
        }
        __syncthreads();
        half8 afr[4], bfr[4];
#pragma unroll
        for (int i = 0; i < 4; i++) afr[i] = *(half8*)&As[(wm * 64 + i * 16 + l16) * LDP + q * 8];
#pragma unroll
        for (int j = 0; j < 4; j++) bfr[j] = *(half8*)&Bs[(wn * 64 + j * 16 + l16) * LDP + q * 8];
#pragma unroll
        for (int i = 0; i < 4; i++)
#pragma unroll
            for (int j = 0; j < 4; j++)
                acc[i][j] = __builtin_amdgcn_mfma_f32_16x16x32_f16(afr[i], bfr[j], acc[i][j], 0, 0, 0);
        __syncthreads();
    }
#pragma unroll
    for (int i = 0; i < 4; i++) {
#pragma unroll
        for (int r = 0; r < 4; r++) {
            int row = bm + wm * 64 + i * 16 + q * 4 + r;
            if (row < n) {
                float sc = scale[row];
#pragma unroll
                for (int j = 0; j < 4; j++) {
                    int col = bn + wn * 64 + j * 16 + l16;
                    Cout[(size_t)row * M + col] = (f16)(acc[i][j][r] * sc);
                }
            }
        }
    }
}

// ============ attention GEMM: fused BN staging + leaky+Wa2 epilogue + atomicMax, writes Af ============
__global__ __launch_bounds__(256) void gemm_attn_kernel(const f16* __restrict__ Ch, const f16* __restrict__ Aold,
                                                        f16* __restrict__ Afout, const float* __restrict__ affine,
                                                        const f16* __restrict__ Wt,
                                                        const float* __restrict__ ba1, const float* __restrict__ Wa2,
                                                        const float* __restrict__ ba2, float* __restrict__ score,
                                                        int* __restrict__ maxkey, int n, int K) {
    __shared__ __align__(16) f16 As[BM * LDP];
    __shared__ __align__(16) f16 Bs[128 * LDP];
    __shared__ float sA[256], sB[256];
    __shared__ float scred[128][2];
    int tid = threadIdx.x;
    if (tid < 256) { sA[tid] = affine[tid]; sB[tid] = affine[256 + tid]; }
    int wave = tid >> 6, lane = tid & 63;
    int wm = wave >> 1, wn = wave & 1;
    int q = lane >> 4, l16 = lane & 15;
    int bm = blockIdx.x * BM;
    int kc = (tid & 3) * 8;
    floatx4 acc[4][4] = {};
    __syncthreads();
    for (int k0 = 0; k0 < K; k0 += BK) {
        float a8[8], b8[8];
#pragma unroll
        for (int j = 0; j < 8; j++) { a8[j] = sA[k0 + kc + j]; b8[j] = sB[k0 + kc + j]; }
#pragma unroll
        for (int rr = 0; rr < 2; rr++) {
            int cidx = tid + rr * 256;
            int row = cidx >> 2;
            int arow = bm + row; if (arow >= n) arow = n - 1;
            half8 ch = *(const half8*)&Ch[(size_t)arow * K + k0 + kc];
            half8 ao = *(const half8*)&Aold[(size_t)arow * K + k0 + kc];
            half8 af;
#pragma unroll
            for (int j = 0; j < 8; j++)
                af[j] = (f16)(fmaxf((float)ch[j], 0.f) * a8[j] + b8[j] + (float)ao[j]);
            *(float4*)&As[row * LDP + kc] = *(float4*)&af;
            if (bm + row < n) *(half8*)&Afout[(size_t)arow * K + k0 + kc] = af;
            *(float4*)&Bs[row * LDP + kc] = *(const float4*)&Wt[(size_t)row * K + k0 + kc];
        }
        __syncthreads();
        half8 afr[4], bfr[4];
#pragma unroll
        for (int i = 0; i < 4; i++) afr[i] = *(half8*)&As[(wm * 64 + i * 16 + l16) * LDP + q * 8];
#pragma unroll
        for (int j = 0; j < 4; j++) bfr[j] = *(half8*)&Bs[(wn * 64 + j * 16 + l16) * LDP + q * 8];
#pragma unroll
        for (int i = 0; i < 4; i++)
#pragma unroll
            for (int j = 0; j < 4; j++)
                acc[i][j] = __builtin_amdgcn_mfma_f32_16x16x32_f16(afr[i], bfr[j], acc[i][j], 0, 0, 0);
        __syncthreads();
    }
    float ba1v[4], wa2v[4];
#pragma unroll
    for (int j = 0; j < 4; j++) {
        int col = wn * 64 + j * 16 + l16;
        ba1v[j] = ba1[col];
        wa2v[j] = Wa2[col];
    }
#pragma unroll
    for (int i = 0; i < 4; i++)
#pragma unroll
        for (int r = 0; r < 4; r++) {
            float p = 0.f;
#pragma unroll
            for (int j = 0; j < 4; j++) {
                float v = acc[i][j][r] + ba1v[j];
                v = (v > 0.f) ? v : 0.01f * v;
                p += v * wa2v[j];
            }
#pragma unroll
            for (int o = 1; o < 16; o <<= 1) p += __shfl_xor(p, o);
            if (l16 == 0) scred[wm * 64 + i * 16 + q * 4 + r][wn] = p;
        }
    __syncthreads();
    __shared__ float mred[128];
    if (tid < 128) {
        int grow = bm + tid;
        float sc = scred[tid][0] + scred[tid][1] + ba2[0];
        if (grow < n) score[grow] = sc; else sc = -3.0e38f;
        mred[tid] = sc;
    }
    __syncthreads();
    for (int o = 64; o > 0; o >>= 1) {
        if (tid < o && tid + o < 128) mred[tid] = fmaxf(mred[tid], mred[tid + o]);
        __syncthreads();
    }
    if (tid == 0) atomicMax(maxkey, fkey(mred[0]));
}

// pooled[g,c] += striped sum of Af[i,c]*exp(score[i]-mx); also global sum-exp. grid (NG, 8)
__global__ __launch_bounds__(256) void pool_kernel(const f16* __restrict__ Af, const float* __restrict__ score,
                                                   const int* __restrict__ offs, const int* __restrict__ cnts,
                                                   const int* __restrict__ maxkey, float* __restrict__ expsum,
                                                   float* __restrict__ pooled) {
    float mx = keyf(maxkey[0]);
    int c = threadIdx.x;
    int g = blockIdx.x;
    int st = offs[g], cn = cnts[g];
    float acc = 0.f, esum = 0.f;
    for (int i = (int)blockIdx.y; i < cn; i += 32) {
        int i1 = i + 8, i2 = i + 16, i3 = i + 24;
        float s0 = score[st + i];
        float s1 = (i1 < cn) ? score[st + i1] : -3.0e38f;
        float s2 = (i2 < cn) ? score[st + i2] : -3.0e38f;
        float s3 = (i3 < cn) ? score[st + i3] : -3.0e38f;
        float e0 = expf(s0 - mx), e1 = expf(s1 - mx), e2 = expf(s2 - mx), e3 = expf(s3 - mx);
        float a0 = (float)Af[(size_t)(st + i) * DIM + c];
        float a1 = (i1 < cn) ? (float)Af[(size_t)(st + i1) * DIM + c] : 0.f;
        float a2 = (i2 < cn) ? (float)Af[(size_t)(st + i2) * DIM + c] : 0.f;
        float a3 = (i3 < cn) ? (float)Af[(size_t)(st + i3) * DIM + c] : 0.f;
        acc += a0 * e0 + a1 * e1 + a2 * e2 + a3 * e3;
        esum += (e0 + e1) + (e2 + e3);
    }
    atomicAdd(&pooled[g * DIM + c], acc);
    if (c == 0) atomicAdd(expsum, esum);
}

__global__ __launch_bounds__(256) void out_kernel(const float* __restrict__ pooled, const int* __restrict__ cnt,
                                                  const float* __restrict__ expsum, const float* __restrict__ Wo,
                                                  const float* __restrict__ bo, float* __restrict__ out) {
    __shared__ float l0[256], l1[256];
    int g = blockIdx.x, c = threadIdx.x;
    float scale = 1.f / (expsum[0] * fmaxf((float)cnt[g], 1.f));
    float v = pooled[g * DIM + c] * scale;
    l0[c] = v * Wo[c * 2];
    l1[c] = v * Wo[c * 2 + 1];
    __syncthreads();
    for (int o = 128; o > 0; o >>= 1) {
        if (c < o) { l0[c] += l0[c + o]; l1[c] += l1[c + o]; }
        __syncthreads();
    }
    if (c == 0) { out[g * 2] = l0[0] + bo[0]; out[g * 2 + 1] = l1[0] + bo[1]; }
}

// ============================ launch ============================
extern "C" void kernel_launch(void* const* d_in, const int* in_sizes, int n_in,
                              void* d_out, int out_size, void* d_ws, size_t ws_size,
                              hipStream_t stream) {
    const float* x       = (const float*)d_in[0];
    const int*   ei      = (const int*)d_in[1];
    const int*   batch   = (const int*)d_in[2];
    const float* bn_in_g = (const float*)d_in[3];
    const float* bn_in_b = (const float*)d_in[4];
    const float* Ws[3]   = {(const float*)d_in[5],  (const float*)d_in[9],  (const float*)d_in[13]};
    const float* bs[3]   = {(const float*)d_in[6],  (const float*)d_in[10], (const float*)d_in[14]};
    const float* gs[3]   = {(const float*)d_in[7],  (const float*)d_in[11], (const float*)d_in[15]};
    const float* bbs[3]  = {(const float*)d_in[8],  (const float*)d_in[12], (const float*)d_in[16]};
    const float* Wa1 = (const float*)d_in[17];
    const float* ba1 = (const float*)d_in[18];
    const float* Wa2 = (const float*)d_in[19];
    const float* ba2 = (const float*)d_in[20];
    const float* Wo  = (const float*)d_in[21];
    const float* bo  = (const float*)d_in[22];

    char* w = (char*)d_ws;
    size_t off = 0;
    auto alloc = [&](size_t bytes) -> void* {
        void* p = w + off;
        off += (bytes + 255) & ~(size_t)255;
        return p;
    };
    // --- zeroed region (single memset): deg, pooled, expsum ---
    int*   deg     = (int*)alloc((size_t)N_NODES * 4);
    float* pooled  = (float*)alloc((size_t)NG * DIM * 4);
    float* expsum  = (float*)alloc(4);
    size_t zero_span = off;
    // --- rest ---
    float* stats_part = (float*)alloc((size_t)NB_COL * 512 * 4);  // also holds NRG*8*64 layer partials
    float* affine  = (float*)alloc(512 * 4);
    f16*   AfA  = (f16*)alloc((size_t)N_NODES * DIM * 2);
    f16*   AfB  = (f16*)alloc((size_t)N_NODES * DIM * 2);
    f16*   Bh   = (f16*)alloc((size_t)N_NODES * DIM * 2);   // hscaled
    f16*   Chb  = (f16*)alloc((size_t)N_NODES * DIM * 2);   // aggregated pre-BN
    f16*   Wt[3];
    for (int l = 0; l < 3; l++) Wt[l] = (f16*)alloc((size_t)DIM * DIM * 2);
    f16*   Wa1t = (f16*)alloc((size_t)128 * DIM * 2);
    int* sorted_src = (int*)alloc((size_t)N_EDGES * 4);
    int* lpos   = (int*)alloc((size_t)N_EDGES * 4);
    float* dinv = (float*)alloc((size_t)N_NODES * 4);
    int* rowp   = (int*)alloc((size_t)(N_NODES + 1) * 4);
    float* score = (float*)alloc((size_t)N_NODES * 4);
    int* bsums   = (int*)alloc(64 * 4);
    int* maxkey  = (int*)alloc(16);
    int* gstart  = (int*)alloc(64 * 4);
    int* cnt_g   = (int*)alloc(64 * 4);
    int* off_g   = (int*)alloc(64 * 4);

    const int* src = ei;
    const int* dst = ei + N_EDGES;
    const int NSCAN = (N_NODES + SCHUNK - 1) / SCHUNK;
    const float inv_n = 1.f / N_NODES;

    hipMemsetAsync(d_ws, 0, zero_span, stream);
    hipMemsetAsync(gstart, 0xff, 64 * 4, stream);

    // ---- CSR build (atomic count saves lpos; scatter atomic-free) + graph bounds ----
    count_bounds_kernel<<<NB_AGG + 196, 256, 0, stream>>>(dst, N_EDGES, deg, lpos, batch, N_NODES, gstart);
    scan1_kernel<<<NSCAN, 256, 0, stream>>>(deg, N_NODES, rowp, bsums, dinv);
    scan3_kernel<<<(N_NODES + 255) / 256, 256, 0, stream>>>(rowp, bsums, N_NODES, N_EDGES);
    scatter_kernel<<<NB_AGG, 256, 0, stream>>>(src, dst, lpos, N_EDGES, rowp, sorted_src);
    graph_offsets2_kernel<<<1, 64, 0, stream>>>(gstart, off_g, cnt_g, maxkey);

    // ---- weights ----
    convert_all_kernel<<<896, 256, 0, stream>>>(Ws[0], Ws[1], Ws[2], Wa1, Wt[0], Wt[1], Wt[2], Wa1t);

    // ---- input BN stats -> affine ----
    col_stats_kernel<<<NB_COL, 256, 0, stream>>>(x, N_NODES, stats_part);
    reduce_in_finalize_kernel<<<1, 256, 0, stream>>>(stats_part, bn_in_g, bn_in_b, affine, inv_n);

    // ---- GCN layers ----
    dim3 ggrid((N_NODES + BM - 1) / BM, DIM / BN);
    // layer 0
    gemm_fused_kernel<<<ggrid, 256, 0, stream>>>(x, nullptr, nullptr, nullptr, affine, Wt[0], Bh, dinv, N_NODES, DIM, DIM);
    gcn_agg_kernel<<<NRG * 8, 256, 0, stream>>>(Bh, rowp, sorted_src, dinv, bs[0], Chb, stats_part, N_NODES);
    reduce_agg_finalize_kernel<<<1, 256, 0, stream>>>(stats_part, gs[0], bbs[0], affine, inv_n);
    // layer 1
    gemm_fused_kernel<<<ggrid, 256, 0, stream>>>(nullptr, Chb, nullptr, AfA, affine, Wt[1], Bh, dinv, N_NODES, DIM, DIM);
    gcn_agg_kernel<<<NRG * 8, 256, 0, stream>>>(Bh, rowp, sorted_src, dinv, bs[1], Chb, stats_part, N_NODES);
    reduce_agg_finalize_kernel<<<1, 256, 0, stream>>>(stats_part, gs[1], bbs[1], affine, inv_n);
    // layer 2
    gemm_fused_kernel<<<ggrid, 256, 0, stream>>>(nullptr, Chb, AfA, AfB, affine, Wt[2], Bh, dinv, N_NODES, DIM, DIM);
    gcn_agg_kernel<<<NRG * 8, 256, 0, stream>>>(Bh, rowp, sorted_src, dinv, bs[2], Chb, stats_part, N_NODES);
    reduce_agg_finalize_kernel<<<1, 256, 0, stream>>>(stats_part, gs[2], bbs[2], affine, inv_n);

    // ---- attention ----
    gemm_attn_kernel<<<(N_NODES + BM - 1) / BM, 256, 0, stream>>>(Chb, AfB, AfA, affine, Wa1t,
                                                                  ba1, Wa2, ba2, score, maxkey, N_NODES, DIM);

    // ---- pooling + output ----
    pool_kernel<<<dim3(NG, 8), 256, 0, stream>>>(AfA, score, off_g, cnt_g, maxkey, expsum, pooled);
    out_kernel<<<NG, 256, 0, stream>>>(pooled, cnt_g, expsum, Wo, bo, (float*)d_out);
}

// Round 10
// 702.487 us; speedup vs baseline: 1.6875x; 1.6875x over previous
//
#include <hip/hip_runtime.h>

#define N_NODES 50000
#define N_EDGES 800000
#define DIM 256
#define NG 64
#define EPS_BN 1e-5f
#define NB_AGG 3125
#define NB_COL 512
#define NSPLIT 32

typedef _Float16 f16;
typedef _Float16 half8 __attribute__((ext_vector_type(8)));
typedef _Float16 half4 __attribute__((ext_vector_type(4)));
typedef float floatx4 __attribute__((ext_vector_type(4)));

__device__ __forceinline__ int fkey(float f) { int i = __float_as_int(f); return (i >= 0) ? i : (i ^ 0x7fffffff); }
__device__ __forceinline__ float keyf(int k) { return __int_as_float((k >= 0) ? k : (k ^ 0x7fffffff)); }

// ============================ input BN statistics -> coalesced per-block partials ============================
__global__ __launch_bounds__(256) void col_stats_kernel(const float* __restrict__ X, int n,
                                                        float* __restrict__ part) {
    int c = threadIdx.x;
    float s = 0.f, q = 0.f;
    for (int i = blockIdx.x; i < n; i += gridDim.x) {
        float v = X[(size_t)i * DIM + c];
        s += v; q += v * v;
    }
    part[(size_t)blockIdx.x * 512 + c] = s;
    part[(size_t)blockIdx.x * 512 + DIM + c] = q;
}

// ============ merged level-1 reduce + (last block) finalize -> affine A[c]=rstd*g, B[c]=b-mean*A ============
__global__ __launch_bounds__(256) void reduce_finalize_kernel(const float* __restrict__ part, int nrows,
                                                              float* __restrict__ p2, int* __restrict__ counter,
                                                              const float* __restrict__ g, const float* __restrict__ b,
                                                              float* __restrict__ affine, float inv_n) {
    int col = blockIdx.x * 256 + threadIdx.x;   // grid.x = 2 -> 0..511
    int chunk = (nrows + NSPLIT - 1) / NSPLIT;
    int r0 = blockIdx.y * chunk;
    int r1 = min(r0 + chunk, nrows);
    float t = 0.f;
    for (int r = r0; r < r1; r++) t += part[(size_t)r * 512 + col];
    p2[(size_t)blockIdx.y * 512 + col] = t;
    __threadfence();
    __shared__ int lastf;
    if (threadIdx.x == 0) lastf = (atomicAdd(counter, 1) == 2 * NSPLIT - 1) ? 1 : 0;
    __syncthreads();
    if (lastf) {
        __threadfence();
        int c = threadIdx.x;
        float s = 0.f, q = 0.f;
#pragma unroll
        for (int r = 0; r < NSPLIT; r++) {
            s += p2[(size_t)r * 512 + c];
            q += p2[(size_t)r * 512 + DIM + c];
        }
        float m = s * inv_n;
        float v = q * inv_n - m * m;
        float rstd = rsqrtf(v + EPS_BN);
        float A = rstd * g[c];
        affine[c] = A;
        affine[DIM + c] = b[c] - m * A;
    }
}

// ============================ weight conversion, all 4 in one ============================
__global__ void convert_all_kernel(const float* __restrict__ W0, const float* __restrict__ W1,
                                   const float* __restrict__ W2, const float* __restrict__ Wa1,
                                   f16* __restrict__ T0, f16* __restrict__ T1,
                                   f16* __restrict__ T2, f16* __restrict__ T3) {
    int idx = blockIdx.x * 256 + threadIdx.x;
    if (idx < 196608) {
        int w = idx >> 16, r = idx & 65535;
        const float* W = (w == 0) ? W0 : (w == 1) ? W1 : W2;
        f16* T = (w == 0) ? T0 : (w == 1) ? T1 : T2;
        int m = r >> 8, k = r & 255;
        T[r] = (f16)W[(size_t)k * 256 + m];
    } else {
        int r = idx - 196608;
        int m = r >> 8, k = r & 255;
        T3[r] = (f16)Wa1[(size_t)k * 128 + m];
    }
}

// ============== degree histogram (saving local positions) + graph bounds (merged) ==============
__global__ void count_bounds_kernel(const int* __restrict__ dst, int ne, int* __restrict__ cnt,
                                    int* __restrict__ lpos,
                                    const int* __restrict__ batch, int n, int* __restrict__ start) {
    int gb = blockIdx.x;
    if (gb < NB_AGG) {
        for (int i = gb * 256 + threadIdx.x; i < ne; i += NB_AGG * 256)
            lpos[i] = atomicAdd(&cnt[dst[i]], 1);
    } else {
        int i = (gb - NB_AGG) * 256 + threadIdx.x;
        if (i < n) {
            int b = batch[i];
            if (i == 0 || batch[i - 1] != b) start[b] = i;
        }
    }
}

#define SCHUNK 2048
__global__ __launch_bounds__(256) void scan1_kernel(const int* __restrict__ cnt, int n,
                                                    int* __restrict__ outp, int* __restrict__ bsums,
                                                    float* __restrict__ dinv) {
    __shared__ int lds[256];
    int t = threadIdx.x;
    int base = blockIdx.x * SCHUNK + t * 8;
    int v[8]; int s = 0;
#pragma unroll
    for (int j = 0; j < 8; j++) {
        int id = base + j;
        int x = 0;
        if (id < n) { x = cnt[id]; dinv[id] = rsqrtf((float)x + 1.0f); }
        v[j] = s; s += x;
    }
    lds[t] = s; __syncthreads();
    for (int o = 1; o < 256; o <<= 1) {
        int add = (t >= o) ? lds[t - o] : 0;
        __syncthreads();
        lds[t] += add;
        __syncthreads();
    }
    int excl = lds[t] - s;
#pragma unroll
    for (int j = 0; j < 8; j++) { int id = base + j; if (id < n) outp[id] = excl + v[j]; }
    if (t == 255) bsums[blockIdx.x] = lds[255];
}

__global__ void scan3_kernel(int* __restrict__ outp, const int* __restrict__ bsums, int n, int total) {
    int i = blockIdx.x * blockDim.x + threadIdx.x;
    if (i < n) {
        int k = i / SCHUNK;
        int pref = 0;
        for (int j = 0; j < k; j++) pref += bsums[j];
        outp[i] += pref;
    }
    if (i == 0) outp[n] = total;
}

// atomic-free scatter using saved local positions
__global__ void scatter_kernel(const int* __restrict__ src, const int* __restrict__ dst,
                               const int* __restrict__ lpos, int ne,
                               const int* __restrict__ rowp, int* __restrict__ ss) {
    for (int e = blockIdx.x * blockDim.x + threadIdx.x; e < ne; e += gridDim.x * blockDim.x)
        ss[rowp[dst[e]] + lpos[e]] = src[e];
}

__global__ void graph_offsets2_kernel(const int* __restrict__ start, int* __restrict__ off, int* __restrict__ cnt,
                                      int* __restrict__ maxkey) {
    if (threadIdx.x == 0 && blockIdx.x == 0) {
        int nxt = N_NODES;
        for (int g = NG - 1; g >= 0; --g) {
            int s = start[g];
            int o = (s < 0) ? nxt : s;
            off[g] = o;
            cnt[g] = nxt - o;
            nxt = o;
        }
        maxkey[0] = 0x80000000;
    }
}

// ============================ GCN edge aggregation (round-7 structure: full-row half4 gather) ============================
// h is pre-scaled by dinv. out = dinv[row]*(sum_src h + h[row]) + bias
// writes Ch (fp16, pre-relu) AND coalesced per-block BN-stat partials of relu(Ch)
__global__ __launch_bounds__(256) void gcn_agg_kernel(const f16* __restrict__ h, const int* __restrict__ rowp,
                                                      const int* __restrict__ ss, const float* __restrict__ dinv,
                                                      const float* __restrict__ bias, f16* __restrict__ out,
                                                      float* __restrict__ part, int n) {
    int wave = threadIdx.x >> 6;
    int lane = threadIdx.x & 63;
    int c = lane * 4;
    float4 bv = *(const float4*)&bias[c];
    float s0a = 0.f, s1a = 0.f, s2a = 0.f, s3a = 0.f;
    float q0a = 0.f, q1a = 0.f, q2a = 0.f, q3a = 0.f;
    for (int row = blockIdx.x * 4 + wave; row < n; row += gridDim.x * 4) {
        float ax = 0.f, ay = 0.f, az = 0.f, aw = 0.f;
        int e0 = rowp[row], e1 = rowp[row + 1];
        int e = e0;
        for (; e + 3 < e1; e += 4) {
            int i0 = ss[e], i1 = ss[e + 1], i2 = ss[e + 2], i3 = ss[e + 3];
            half4 h0 = *(const half4*)&h[((size_t)i0 << 8) + c];
            half4 h1 = *(const half4*)&h[((size_t)i1 << 8) + c];
            half4 h2 = *(const half4*)&h[((size_t)i2 << 8) + c];
            half4 h3 = *(const half4*)&h[((size_t)i3 << 8) + c];
            ax += ((float)h0[0] + (float)h1[0]) + ((float)h2[0] + (float)h3[0]);
            ay += ((float)h0[1] + (float)h1[1]) + ((float)h2[1] + (float)h3[1]);
            az += ((float)h0[2] + (float)h1[2]) + ((float)h2[2] + (float)h3[2]);
            aw += ((float)h0[3] + (float)h1[3]) + ((float)h2[3] + (float)h3[3]);
        }
        for (; e < e1; e++) {
            int si = ss[e];
            half4 hv = *(const half4*)&h[((size_t)si << 8) + c];
            ax += (float)hv[0]; ay += (float)hv[1]; az += (float)hv[2]; aw += (float)hv[3];
        }
        float di = dinv[row];
        half4 hs = *(const half4*)&h[((size_t)row << 8) + c];
        float rx = di * (ax + (float)hs[0]) + bv.x;
        float ry = di * (ay + (float)hs[1]) + bv.y;
        float rz = di * (az + (float)hs[2]) + bv.z;
        float rw = di * (aw + (float)hs[3]) + bv.w;
        half4 o; o[0] = (f16)rx; o[1] = (f16)ry; o[2] = (f16)rz; o[3] = (f16)rw;
        *(half4*)&out[((size_t)row << 8) + c] = o;
        float t;
        t = fmaxf(rx, 0.f); s0a += t; q0a += t * t;
        t = fmaxf(ry, 0.f); s1a += t; q1a += t * t;
        t = fmaxf(rz, 0.f); s2a += t; q2a += t * t;
        t = fmaxf(rw, 0.f); s3a += t; q3a += t * t;
    }
    __shared__ float sred[4][64][4];
    __shared__ float qred[4][64][4];
    sred[wave][lane][0] = s0a; sred[wave][lane][1] = s1a; sred[wave][lane][2] = s2a; sred[wave][lane][3] = s3a;
    qred[wave][lane][0] = q0a; qred[wave][lane][1] = q1a; qred[wave][lane][2] = q2a; qred[wave][lane][3] = q3a;
    __syncthreads();
    if (wave == 0) {
        size_t base = (size_t)blockIdx.x * 512;
        float4 a = make_float4(0.f, 0.f, 0.f, 0.f), qv = make_float4(0.f, 0.f, 0.f, 0.f);
#pragma unroll
        for (int ww = 0; ww < 4; ww++) {
            a.x += sred[ww][lane][0]; a.y += sred[ww][lane][1]; a.z += sred[ww][lane][2]; a.w += sred[ww][lane][3];
            qv.x += qred[ww][lane][0]; qv.y += qred[ww][lane][1]; qv.z += qred[ww][lane][2]; qv.w += qred[ww][lane][3];
        }
        *(float4*)&part[base + c] = a;
        *(float4*)&part[base + DIM + c] = qv;
    }
}

// ============================ fused BN + MFMA GEMM ============================
#define BM 128
#define BN 128
#define BK 32
#define LDP 40
__global__ __launch_bounds__(256) void gemm_fused_kernel(const float* __restrict__ Xf32, const f16* __restrict__ Ch,
                                                         const f16* __restrict__ Aold, f16* __restrict__ Afout,
                                                         const float* __restrict__ affine,
                                                         const f16* __restrict__ Wt, f16* __restrict__ Cout,
                                                         const float* __restrict__ scale, int n, int K, int M) {
    __shared__ __align__(16) f16 As[BM * LDP];
    __shared__ __align__(16) f16 Bs[BN * LDP];
    __shared__ float sA[256], sB[256];
    int tid = threadIdx.x;
    if (tid < 256) { sA[tid] = affine[tid]; sB[tid] = affine[256 + tid]; }
    int wave = tid >> 6, lane = tid & 63;
    int wm = wave >> 1, wn = wave & 1;
    int q = lane >> 4, l16 = lane & 15;
    int bm = blockIdx.x * BM, bn = blockIdx.y * BN;
    int kc = (tid & 3) * 8;
    int writer = (Afout != nullptr) && (blockIdx.y == 0);
    floatx4 acc[4][4] = {};
    __syncthreads();
    for (int k0 = 0; k0 < K; k0 += BK) {
        float a8[8], b8[8];
#pragma unroll
        for (int j = 0; j < 8; j++) { a8[j] = sA[k0 + kc + j]; b8[j] = sB[k0 + kc + j]; }
#pragma unroll
        for (int rr = 0; rr < 2; rr++) {
            int cidx = tid + rr * 256;
            int row = cidx >> 2;
            int arow = bm + row; if (arow >= n) arow = n - 1;
            float v[8];
            if (Xf32) {
                float4 x0 = *(const float4*)&Xf32[(size_t)arow * K + k0 + kc];
                float4 x1 = *(const float4*)&Xf32[(size_t)arow * K + k0 + kc + 4];
                v[0] = x0.x; v[1] = x0.y; v[2] = x0.z; v[3] = x0.w;
                v[4] = x1.x; v[5] = x1.y; v[6] = x1.z; v[7] = x1.w;
            } else {
                half8 ch = *(const half8*)&Ch[(size_t)arow * K + k0 + kc];
#pragma unroll
                for (int j = 0; j < 8; j++) v[j] = fmaxf((float)ch[j], 0.f);
            }
            half8 af;
            if (Aold) {
                half8 ao = *(const half8*)&Aold[(size_t)arow * K + k0 + kc];
#pragma unroll
                for (int j = 0; j < 8; j++) af[j] = (f16)(v[j] * a8[j] + b8[j] + (float)ao[j]);
            } else {
#pragma unroll
                for (int j = 0; j < 8; j++) af[j] = (f16)(v[j] * a8[j] + b8[j]);
            }
            *(float4*)&As[row * LDP + kc] = *(float4*)&af;
            if (writer && bm + row < n) *(half8*)&Afout[(size_t)arow * K + k0 + kc] = af;
            int brow = bn + row;
            *(float4*)&Bs[row * LDP + kc] = *(const float4*)&Wt[(size_t)brow * K + k0 + kc];
        }
        __syncthreads();
        half8 afr[4], bfr[4];
#pragma unroll
        for (int i = 0; i < 4; i++) afr[i] = *(half8*)&As[(wm * 64 + i * 16 + l16) * LDP + q * 8];
#pragma unroll
        for (int j = 0; j < 4; j++) bfr[j] = *(half8*)&Bs[(wn * 64 + j * 16 + l16) * LDP + q * 8];
#pragma unroll
        for (int i = 0; i < 4; i++)
#pragma unroll
            for (int j = 0; j < 4; j++)
                acc[i][j] = __builtin_amdgcn_mfma_f32_16x16x32_f16(afr[i], bfr[j], acc[i][j], 0, 0, 0);
        __syncthreads();
    }
#pragma unroll
    for (int i = 0; i < 4; i++) {
#pragma unroll
        for (int r = 0; r < 4; r++) {
            int row = bm + wm * 64 + i * 16 + q * 4 + r;
            if (row < n) {
                float sc = scale[row];
#pragma unroll
                for (int j = 0; j < 4; j++) {
                    int col = bn + wn * 64 + j * 16 + l16;
                    Cout[(size_t)row * M + col] = (f16)(acc[i][j][r] * sc);
                }
            }
        }
    }
}

// ============ attention GEMM: fused BN staging + leaky+Wa2 epilogue + atomicMax, writes Af ============
__global__ __launch_bounds__(256) void gemm_attn_kernel(const f16* __restrict__ Ch, const f16* __restrict__ Aold,
                                                        f16* __restrict__ Afout, const float* __restrict__ affine,
                                                        const f16* __restrict__ Wt,
                                                        const float* __restrict__ ba1, const float* __restrict__ Wa2,
                                                        const float* __restrict__ ba2, float* __restrict__ score,
                                                        int* __restrict__ maxkey, int n, int K) {
    __shared__ __align__(16) f16 As[BM * LDP];
    __shared__ __align__(16) f16 Bs[128 * LDP];
    __shared__ float sA[256], sB[256];
    __shared__ float scred[128][2];
    int tid = threadIdx.x;
    if (tid < 256) { sA[tid] = affine[tid]; sB[tid] = affine[256 + tid]; }
    int wave = tid >> 6, lane = tid & 63;
    int wm = wave >> 1, wn = wave & 1;
    int q = lane >> 4, l16 = lane & 15;
    int bm = blockIdx.x * BM;
    int kc = (tid & 3) * 8;
    floatx4 acc[4][4] = {};
    __syncthreads();
    for (int k0 = 0; k0 < K; k0 += BK) {
        float a8[8], b8[8];
#pragma unroll
        for (int j = 0; j < 8; j++) { a8[j] = sA[k0 + kc + j]; b8[j] = sB[k0 + kc + j]; }
#pragma unroll
        for (int rr = 0; rr < 2; rr++) {
            int cidx = tid + rr * 256;
            int row = cidx >> 2;
            int arow = bm + row; if (arow >= n) arow = n - 1;
            half8 ch = *(const half8*)&Ch[(size_t)arow * K + k0 + kc];
            half8 ao = *(const half8*)&Aold[(size_t)arow * K + k0 + kc];
            half8 af;
#pragma unroll
            for (int j = 0; j < 8; j++)
                af[j] = (f16)(fmaxf((float)ch[j], 0.f) * a8[j] + b8[j] + (float)ao[j]);
            *(float4*)&As[row * LDP + kc] = *(float4*)&af;
            if (bm + row < n) *(half8*)&Afout[(size_t)arow * K + k0 + kc] = af;
            *(float4*)&Bs[row * LDP + kc] = *(const float4*)&Wt[(size_t)row * K + k0 + kc];
        }
        __syncthreads();
        half8 afr[4], bfr[4];
#pragma unroll
        for (int i = 0; i < 4; i++) afr[i] = *(half8*)&As[(wm * 64 + i * 16 + l16) * LDP + q * 8];
#pragma unroll
        for (int j = 0; j < 4; j++) bfr[j] = *(half8*)&Bs[(wn * 64 + j * 16 + l16) * LDP + q * 8];
#pragma unroll
        for (int i = 0; i < 4; i++)
#pragma unroll
            for (int j = 0; j < 4; j++)
                acc[i][j] = __builtin_amdgcn_mfma_f32_16x16x32_f16(afr[i], bfr[j], acc[i][j], 0, 0, 0);
        __syncthreads();
    }
    float ba1v[4], wa2v[4];
#pragma unroll
    for (int j = 0; j < 4; j++) {
        int col = wn * 64 + j * 16 + l16;
        ba1v[j] = ba1[col];
        wa2v[j] = Wa2[col];
    }
#pragma unroll
    for (int i = 0; i < 4; i++)
#pragma unroll
        for (int r = 0; r < 4; r++) {
            float p = 0.f;
#pragma unroll
            for (int j = 0; j < 4; j++) {
                float v = acc[i][j][r] + ba1v[j];
                v = (v > 0.f) ? v : 0.01f * v;
                p += v * wa2v[j];
            }
#pragma unroll
            for (int o = 1; o < 16; o <<= 1) p += __shfl_xor(p, o);
            if (l16 == 0) scred[wm * 64 + i * 16 + q * 4 + r][wn] = p;
        }
    __syncthreads();
    __shared__ float mred[128];
    if (tid < 128) {
        int grow = bm + tid;
        float sc = scred[tid][0] + scred[tid][1] + ba2[0];
        if (grow < n) score[grow] = sc; else sc = -3.0e38f;
        mred[tid] = sc;
    }
    __syncthreads();
    for (int o = 64; o > 0; o >>= 1) {
        if (tid < o && tid + o < 128) mred[tid] = fmaxf(mred[tid], mred[tid + o]);
        __syncthreads();
    }
    if (tid == 0) atomicMax(maxkey, fkey(mred[0]));
}

// pooled[g,c] += striped sum of Af[i,c]*exp(score[i]-mx); also global sum-exp. grid (NG, 8)
__global__ __launch_bounds__(256) void pool_kernel(const f16* __restrict__ Af, const float* __restrict__ score,
                                                   const int* __restrict__ offs, const int* __restrict__ cnts,
                                                   const int* __restrict__ maxkey, float* __restrict__ expsum,
                                                   float* __restrict__ pooled) {
    float mx = keyf(maxkey[0]);
    int c = threadIdx.x;
    int g = blockIdx.x;
    int st = offs[g], cn = cnts[g];
    float acc = 0.f, esum = 0.f;
    for (int i = (int)blockIdx.y; i < cn; i += 32) {
        int i1 = i + 8, i2 = i + 16, i3 = i + 24;
        float s0 = score[st + i];
        float s1 = (i1 < cn) ? score[st + i1] : -3.0e38f;
        float s2 = (i2 < cn) ? score[st + i2] : -3.0e38f;
        float s3 = (i3 < cn) ? score[st + i3] : -3.0e38f;
        float e0 = expf(s0 - mx), e1 = expf(s1 - mx), e2 = expf(s2 - mx), e3 = expf(s3 - mx);
        float a0 = (float)Af[(size_t)(st + i) * DIM + c];
        float a1 = (i1 < cn) ? (float)Af[(size_t)(st + i1) * DIM + c] : 0.f;
        float a2 = (i2 < cn) ? (float)Af[(size_t)(st + i2) * DIM + c] : 0.f;
        float a3 = (i3 < cn) ? (float)Af[(size_t)(st + i3) * DIM + c] : 0.f;
        acc += a0 * e0 + a1 * e1 + a2 * e2 + a3 * e3;
        esum += (e0 + e1) + (e2 + e3);
    }
    atomicAdd(&pooled[g * DIM + c], acc);
    if (c == 0) atomicAdd(expsum, esum);
}

__global__ __launch_bounds__(256) void out_kernel(const float* __restrict__ pooled, const int* __restrict__ cnt,
                                                  const float* __restrict__ expsum, const float* __restrict__ Wo,
                                                  const float* __restrict__ bo, float* __restrict__ out) {
    __shared__ float l0[256], l1[256];
    int g = blockIdx.x, c = threadIdx.x;
    float scale = 1.f / (expsum[0] * fmaxf((float)cnt[g], 1.f));
    float v = pooled[g * DIM + c] * scale;
    l0[c] = v * Wo[c * 2];
    l1[c] = v * Wo[c * 2 + 1];
    __syncthreads();
    for (int o = 128; o > 0; o >>= 1) {
        if (c < o) { l0[c] += l0[c + o]; l1[c] += l1[c + o]; }
        __syncthreads();
    }
    if (c == 0) { out[g * 2] = l0[0] + bo[0]; out[g * 2 + 1] = l1[0] + bo[1]; }
}

// ============================ launch ============================
extern "C" void kernel_launch(void* const* d_in, const int* in_sizes, int n_in,
                              void* d_out, int out_size, void* d_ws, size_t ws_size,
                              hipStream_t stream) {
    const float* x       = (const float*)d_in[0];
    const int*   ei      = (const int*)d_in[1];
    const int*   batch   = (const int*)d_in[2];
    const float* bn_in_g = (const float*)d_in[3];
    const float* bn_in_b = (const float*)d_in[4];
    const float* Ws[3]   = {(const float*)d_in[5],  (const float*)d_in[9],  (const float*)d_in[13]};
    const float* bs[3]   = {(const float*)d_in[6],  (const float*)d_in[10], (const float*)d_in[14]};
    const float* gs[3]   = {(const float*)d_in[7],  (const float*)d_in[11], (const float*)d_in[15]};
    const float* bbs[3]  = {(const float*)d_in[8],  (const float*)d_in[12], (const float*)d_in[16]};
    const float* Wa1 = (const float*)d_in[17];
    const float* ba1 = (const float*)d_in[18];
    const float* Wa2 = (const float*)d_in[19];
    const float* ba2 = (const float*)d_in[20];
    const float* Wo  = (const float*)d_in[21];
    const float* bo  = (const float*)d_in[22];

    char* w = (char*)d_ws;
    size_t off = 0;
    auto alloc = [&](size_t bytes) -> void* {
        void* p = w + off;
        off += (bytes + 255) & ~(size_t)255;
        return p;
    };
    // --- zeroed region (single memset): deg, pooled, counters, expsum ---
    int*   deg     = (int*)alloc((size_t)N_NODES * 4);
    float* pooled  = (float*)alloc((size_t)NG * DIM * 4);
    int*   counters = (int*)alloc(4 * 4);
    float* expsum  = (float*)alloc(4);
    size_t zero_span = off;
    // --- rest ---
    float* stats_part = (float*)alloc((size_t)NB_AGG * 512 * 4);
    float* stats_p2   = (float*)alloc((size_t)NSPLIT * 512 * 4);
    float* affine  = (float*)alloc(512 * 4);
    f16*   AfA  = (f16*)alloc((size_t)N_NODES * DIM * 2);
    f16*   AfB  = (f16*)alloc((size_t)N_NODES * DIM * 2);
    f16*   Bh   = (f16*)alloc((size_t)N_NODES * DIM * 2);   // hscaled
    f16*   Chb  = (f16*)alloc((size_t)N_NODES * DIM * 2);   // aggregated pre-BN
    f16*   Wt[3];
    for (int l = 0; l < 3; l++) Wt[l] = (f16*)alloc((size_t)DIM * DIM * 2);
    f16*   Wa1t = (f16*)alloc((size_t)128 * DIM * 2);
    int* sorted_src = (int*)alloc((size_t)N_EDGES * 4);
    int* lpos   = (int*)alloc((size_t)N_EDGES * 4);
    float* dinv = (float*)alloc((size_t)N_NODES * 4);
    int* rowp   = (int*)alloc((size_t)(N_NODES + 1) * 4);
    float* score = (float*)alloc((size_t)N_NODES * 4);
    int* bsums   = (int*)alloc(64 * 4);
    int* maxkey  = (int*)alloc(16);
    int* gstart  = (int*)alloc(64 * 4);
    int* cnt_g   = (int*)alloc(64 * 4);
    int* off_g   = (int*)alloc(64 * 4);

    const int* src = ei;
    const int* dst = ei + N_EDGES;
    const int NSCAN = (N_NODES + SCHUNK - 1) / SCHUNK;
    const float inv_n = 1.f / N_NODES;

    hipMemsetAsync(d_ws, 0, zero_span, stream);
    hipMemsetAsync(gstart, 0xff, 64 * 4, stream);

    // ---- CSR build (atomic count saves lpos; scatter atomic-free) + graph bounds ----
    count_bounds_kernel<<<NB_AGG + 196, 256, 0, stream>>>(dst, N_EDGES, deg, lpos, batch, N_NODES, gstart);
    scan1_kernel<<<NSCAN, 256, 0, stream>>>(deg, N_NODES, rowp, bsums, dinv);
    scan3_kernel<<<(N_NODES + 255) / 256, 256, 0, stream>>>(rowp, bsums, N_NODES, N_EDGES);
    scatter_kernel<<<NB_AGG, 256, 0, stream>>>(src, dst, lpos, N_EDGES, rowp, sorted_src);
    graph_offsets2_kernel<<<1, 64, 0, stream>>>(gstart, off_g, cnt_g, maxkey);

    // ---- weights ----
    convert_all_kernel<<<896, 256, 0, stream>>>(Ws[0], Ws[1], Ws[2], Wa1, Wt[0], Wt[1], Wt[2], Wa1t);

    // ---- input BN stats -> affine ----
    col_stats_kernel<<<NB_COL, 256, 0, stream>>>(x, N_NODES, stats_part);
    reduce_finalize_kernel<<<dim3(2, NSPLIT), 256, 0, stream>>>(stats_part, NB_COL, stats_p2, counters + 0,
                                                                bn_in_g, bn_in_b, affine, inv_n);

    // ---- GCN layers (BN fused into GEMM staging) ----
    dim3 ggrid((N_NODES + BM - 1) / BM, DIM / BN);
    // layer 0
    gemm_fused_kernel<<<ggrid, 256, 0, stream>>>(x, nullptr, nullptr, nullptr, affine, Wt[0], Bh, dinv, N_NODES, DIM, DIM);
    gcn_agg_kernel<<<NB_AGG, 256, 0, stream>>>(Bh, rowp, sorted_src, dinv, bs[0], Chb, stats_part, N_NODES);
    reduce_finalize_kernel<<<dim3(2, NSPLIT), 256, 0, stream>>>(stats_part, NB_AGG, stats_p2, counters + 1,
                                                                gs[0], bbs[0], affine, inv_n);
    // layer 1
    gemm_fused_kernel<<<ggrid, 256, 0, stream>>>(nullptr, Chb, nullptr, AfA, affine, Wt[1], Bh, dinv, N_NODES, DIM, DIM);
    gcn_agg_kernel<<<NB_AGG, 256, 0, stream>>>(Bh, rowp, sorted_src, dinv, bs[1], Chb, stats_part, N_NODES);
    reduce_finalize_kernel<<<dim3(2, NSPLIT), 256, 0, stream>>>(stats_part, NB_AGG, stats_p2, counters + 2,
                                                                gs[1], bbs[1], affine, inv_n);
    // layer 2
    gemm_fused_kernel<<<ggrid, 256, 0, stream>>>(nullptr, Chb, AfA, AfB, affine, Wt[2], Bh, dinv, N_NODES, DIM, DIM);
    gcn_agg_kernel<<<NB_AGG, 256, 0, stream>>>(Bh, rowp, sorted_src, dinv, bs[2], Chb, stats_part, N_NODES);
    reduce_finalize_kernel<<<dim3(2, NSPLIT), 256, 0, stream>>>(stats_part, NB_AGG, stats_p2, counters + 3,
                                                                gs[2], bbs[2], affine, inv_n);

    // ---- attention ----
    gemm_attn_kernel<<<(N_NODES + BM - 1) / BM, 256, 0, stream>>>(Chb, AfB, AfA, affine, Wa1t,
                                                                  ba1, Wa2, ba2, score, maxkey, N_NODES, DIM);

    // ---- pooling + output ----
    pool_kernel<<<dim3(NG, 8), 256, 0, stream>>>(AfA, score, off_g, cnt_g, maxkey, expsum, pooled);
    out_kernel<<<NG, 256, 0, stream>>>(pooled, cnt_g, expsum, Wo, bo, (float*)d_out);
}